// Round 2
// baseline (38.114 us; speedup 1.0000x reference)
//
#include <hip/hip_runtime.h>
#include <hip/hip_bf16.h>

#define C_IN 1024
#define T_SZ 128
#define CTX 64
#define NEV 16
#define BK 64
#define NTILE 16    // C_IN / BK
#define NTHR 512
#define WROW 72     // padded bf16 row stride: 144 B (16B-aligned rows)
#define PLROW 132   // padded P dump row stride (f32 elems)

typedef short bf16x8 __attribute__((ext_vector_type(8)));
typedef float f32x4 __attribute__((ext_vector_type(4)));

__device__ __forceinline__ unsigned short f2bf(float f) {
  __hip_bfloat16 h = __float2bfloat16(f);
  return *(unsigned short*)&h;
}

__global__ __launch_bounds__(NTHR, 1) void fused_sparsify(
    const float* __restrict__ enc,   // [256][1024][128] f32
    const float* __restrict__ wvec,  // [64][1024] f32
    const float* __restrict__ bvec,  // [64] f32
    const float* __restrict__ wsw,   // [1024] f32
    const float* __restrict__ bsw,   // [1] f32
    float* __restrict__ out)         // vecs [256*16*64] ++ sched [256*16*128], f32
{
  const int b    = blockIdx.x;
  const int tid  = threadIdx.x;
  const int lane = tid & 63;
  const int wv   = tid >> 6;   // wave 0..7
  const int g    = lane >> 4;  // k-group 0..3
  const int tl   = lane & 15;
  const int n0   = wv * 16;    // this wave's t-slice

  __shared__ float encb[2][BK][T_SZ];          // 64 KB, linear (global_load_lds dest)
  __shared__ unsigned short Wb[2][CTX][WROW];  // 18.4 KB, padded bf16 (reg-staged+converted)
  __shared__ float wswl[C_IN];
  __shared__ float swpart[NTHR];
  __shared__ float attn[T_SZ];
  __shared__ float topv[NEV];
  __shared__ int   topi[NEV];

  const float* encB = enc + (size_t)b * (C_IN * T_SZ);

  wswl[tid]       = wsw[tid];
  wswl[tid + 512] = wsw[tid + 512];

  f32x4 acc0 = {0.f, 0.f, 0.f, 0.f};
  f32x4 acc1 = acc0, acc2 = acc0, acc3 = acc0;
  float sw_acc = 0.f;

  const int wd = tid >> 3;            // W-stage: row d 0..63
  const int wc = (tid & 7) * 8;       // W-stage: 8 consecutive c per thread

  // ---- prologue: stage tile 0 ----
  {
#pragma unroll
    for (int r = 0; r < 4; ++r) {
      int e = (r * NTHR + tid) * 4;  // f32 elems; 16B per lane
      __builtin_amdgcn_global_load_lds(
          (const __attribute__((address_space(1))) unsigned int*)(encB + e),
          (__attribute__((address_space(3))) unsigned int*)(&encb[0][0][0] + e),
          16, 0, 0);
    }
    float4 w0 = *(const float4*)(wvec + wd * C_IN + wc);
    float4 w1 = *(const float4*)(wvec + wd * C_IN + wc + 4);
    union { bf16x8 v; unsigned short u[8]; } pk;
    pk.u[0] = f2bf(w0.x); pk.u[1] = f2bf(w0.y); pk.u[2] = f2bf(w0.z); pk.u[3] = f2bf(w0.w);
    pk.u[4] = f2bf(w1.x); pk.u[5] = f2bf(w1.y); pk.u[6] = f2bf(w1.z); pk.u[7] = f2bf(w1.w);
    *(bf16x8*)&Wb[0][wd][wc] = pk.v;
  }
  __syncthreads();

  int cur = 0;
  for (int kt = 0; kt < NTILE; ++kt) {
    float4 wr0, wr1;
    const int nxt = cur ^ 1;
    if (kt + 1 < NTILE) {
      const float* gsrc = encB + (kt + 1) * (BK * T_SZ);
#pragma unroll
      for (int r = 0; r < 4; ++r) {
        int e = (r * NTHR + tid) * 4;
        __builtin_amdgcn_global_load_lds(
            (const __attribute__((address_space(1))) unsigned int*)(gsrc + e),
            (__attribute__((address_space(3))) unsigned int*)(&encb[nxt][0][0] + e),
            16, 0, 0);
      }
      wr0 = *(const float4*)(wvec + wd * C_IN + (kt + 1) * BK + wc);
      wr1 = *(const float4*)(wvec + wd * C_IN + (kt + 1) * BK + wc + 4);
    }

    // ---- compute tile kt from buffer cur ----
    const float* ec = &encb[cur][0][0];
    const unsigned short* Wc = &Wb[cur][0][0];
#pragma unroll
    for (int kk = 0; kk < BK; kk += 32) {
      union { bf16x8 v; unsigned short u[8]; } bu;
#pragma unroll
      for (int j = 0; j < 8; ++j)
        bu.u[j] = f2bf(ec[(kk + g * 8 + j) * T_SZ + n0 + tl]);
      bf16x8 a0 = *(const bf16x8*)&Wc[(0 * 16 + tl) * WROW + kk + g * 8];
      bf16x8 a1 = *(const bf16x8*)&Wc[(1 * 16 + tl) * WROW + kk + g * 8];
      bf16x8 a2 = *(const bf16x8*)&Wc[(2 * 16 + tl) * WROW + kk + g * 8];
      bf16x8 a3 = *(const bf16x8*)&Wc[(3 * 16 + tl) * WROW + kk + g * 8];
      acc0 = __builtin_amdgcn_mfma_f32_16x16x32_bf16(a0, bu.v, acc0, 0, 0, 0);
      acc1 = __builtin_amdgcn_mfma_f32_16x16x32_bf16(a1, bu.v, acc1, 0, 0, 0);
      acc2 = __builtin_amdgcn_mfma_f32_16x16x32_bf16(a2, bu.v, acc2, 0, 0, 0);
      acc3 = __builtin_amdgcn_mfma_f32_16x16x32_bf16(a3, bu.v, acc3, 0, 0, 0);
    }
    {
      // switch partial: thread (t = tid&127, cg = tid>>7) covers 16 c's (exact f32)
      const int tsw = tid & 127, cg = tid >> 7;
      const float* wst = wswl + kt * BK + cg * 16;
      const float* ep = ec + (cg * 16) * T_SZ + tsw;
      float s = 0.f;
#pragma unroll
      for (int c = 0; c < 16; ++c)
        s = fmaf(ep[c * T_SZ], wst[c], s);
      sw_acc += s;
    }

    if (kt + 1 < NTILE) {
      union { bf16x8 v; unsigned short u[8]; } pk;
      pk.u[0] = f2bf(wr0.x); pk.u[1] = f2bf(wr0.y); pk.u[2] = f2bf(wr0.z); pk.u[3] = f2bf(wr0.w);
      pk.u[4] = f2bf(wr1.x); pk.u[5] = f2bf(wr1.y); pk.u[6] = f2bf(wr1.z); pk.u[7] = f2bf(wr1.w);
      *(bf16x8*)&Wb[nxt][wd][wc] = pk.v;
    }
    __syncthreads();
    cur ^= 1;
  }

  // ---- switch reduce + bias + relu ----
  swpart[tid] = sw_acc;
  __syncthreads();
  if (tid < T_SZ) {
    float s = swpart[tid] + swpart[tid + 128] + swpart[tid + 256] + swpart[tid + 384];
    s += bsw[0];
    attn[tid] = fmaxf(s, 0.f);
  }
  __syncthreads();

  // ---- top-16 descending, ties -> lower index (wave 0) ----
  if (tid < 64) {
    float v0 = attn[tid], v1 = attn[tid + 64];
#pragma unroll 1
    for (int r = 0; r < NEV; ++r) {
      float bv; int bi;
      if (v0 >= v1) { bv = v0; bi = tid; } else { bv = v1; bi = tid + 64; }
#pragma unroll
      for (int off = 32; off > 0; off >>= 1) {
        float ov = __shfl_xor(bv, off, 64);
        int   oi = __shfl_xor(bi, off, 64);
        if (ov > bv || (ov == bv && oi < bi)) { bv = ov; bi = oi; }
      }
      if (bi == tid) v0 = -__builtin_inff();
      if (bi == tid + 64) v1 = -__builtin_inff();
      if (tid == r) { topv[r] = bv; topi[r] = bi; }
    }
  }
  __syncthreads();

  // ---- dump P (acc frags) to LDS, overlaying encb ----
  float* Pl = (float*)&encb[0][0][0];  // [64][PLROW] f32 = 33.8 KB (encb is dead)
  {
#pragma unroll
    for (int r = 0; r < 4; ++r) {
      Pl[(0 * 16 + 4 * g + r) * PLROW + n0 + tl] = acc0[r];
      Pl[(1 * 16 + 4 * g + r) * PLROW + n0 + tl] = acc1[r];
      Pl[(2 * 16 + 4 * g + r) * PLROW + n0 + tl] = acc2[r];
      Pl[(3 * 16 + 4 * g + r) * PLROW + n0 + tl] = acc3[r];
    }
  }
  __syncthreads();

  // ---- scheduling: out[262144 + b*2048 + j*128 + t] ----
  {
    float* os = out + (256 * NEV * CTX) + b * (NEV * T_SZ);
    int j  = tid >> 5;
    int t0 = (tid * 4) & 127;
    float tv = topv[j];
    int   ti = topi[j];
    float4 v;
    v.x = (t0 + 0 == ti) ? tv : 0.f;
    v.y = (t0 + 1 == ti) ? tv : 0.f;
    v.z = (t0 + 2 == ti) ? tv : 0.f;
    v.w = (t0 + 3 == ti) ? tv : 0.f;
    *(float4*)&os[tid * 4] = v;
  }
  // ---- vecs: out[b*1024 + j*64 + d] = P[d][idx[j]] + b_vec[d] ----
  {
    float* ov = out + b * (NEV * CTX);
#pragma unroll
    for (int s = 0; s < 2; ++s) {
      int o = s * NTHR + tid;
      int j = o >> 6, d = o & 63;
      ov[o] = Pl[d * PLROW + topi[j]] + bvec[d];
    }
  }
}

extern "C" void kernel_launch(void* const* d_in, const int* in_sizes, int n_in,
                              void* d_out, int out_size, void* d_ws, size_t ws_size,
                              hipStream_t stream) {
  const float* enc  = (const float*)d_in[0];
  const float* wvec = (const float*)d_in[1];
  const float* bvec = (const float*)d_in[2];
  const float* wsw  = (const float*)d_in[3];
  const float* bsw  = (const float*)d_in[4];
  float* o = (float*)d_out;
  (void)in_sizes; (void)n_in; (void)out_size; (void)d_ws; (void)ws_size;
  fused_sparsify<<<256, NTHR, 0, stream>>>(enc, wvec, bvec, wsw, bsw, o);
}